// Round 7
// baseline (464.956 us; speedup 1.0000x reference)
//
#include <hip/hip_runtime.h>
#include <hip/hip_bf16.h>

#define M_TOTAL 65536
#define DIM 768
#define KC 64
#define INV_T 10.0f

// k_weighted tiling
#define DT 128    // d-cols per block
#define MB 64     // m per LDS chunk
#define CH 8      // chunks per block (m-range 512)
#define MSEG 128  // m-segments (partials)

#define LOGITS_BLOCKS (M_TOTAL / 64)   // 1024 (64 rows per block)
#define SROWS 128
#define SINK_BLOCKS (M_TOTAL / SROWS)  // 512

typedef __attribute__((ext_vector_type(4))) float f32x4;
typedef __attribute__((ext_vector_type(8))) short bf16x8;
typedef __attribute__((ext_vector_type(4))) unsigned short u16x4;

__device__ __forceinline__ short f2bf(float f) {
    __hip_bfloat16 h = __float2bfloat16(f);
    union { __hip_bfloat16 h; short s; } u; u.h = h;
    return u.s;
}

// ---------------- K0: normalize centers -> cn + cnbf; zero epilogue counters ------
__global__ __launch_bounds__(256) void k_centers(const float* __restrict__ centers,
                                                 float* __restrict__ cn,
                                                 short* __restrict__ cnbf,
                                                 unsigned* __restrict__ cnt) {
    int k = blockIdx.x, tid = threadIdx.x;
    if (k == 0 && tid < 3) cnt[tid] = 0u;
    float ss = 0.f;
    for (int i = tid; i < DIM; i += 256) { float v = centers[k * DIM + i]; ss += v * v; }
    __shared__ float red[4];
    for (int o = 32; o; o >>= 1) ss += __shfl_xor(ss, o);
    if ((tid & 63) == 0) red[tid >> 6] = ss;
    __syncthreads();
    ss = red[0] + red[1] + red[2] + red[3];
    float inv = 1.0f / fmaxf(sqrtf(ss), 1e-12f);
    for (int i = tid; i < DIM; i += 256) {
        float v = centers[k * DIM + i] * inv;
        cn[k * DIM + i] = v;
        cnbf[k * DIM + i] = f2bf(v);
    }
}

// ---------------- K1: logits GEMM (staged) + exp -> E (pre-swizzled), invn --------
// E storage: E[m][c] holds E_true[m][c ^ ((m&15)<<2)]  (bijective within row; only
// k_sink reads E and knows the layout). Last block reduces PS0 -> R0 (no k_redR).
__global__ __launch_bounds__(256) void k_logits(const float* __restrict__ F,
                                                const short* __restrict__ cnbf,
                                                float* __restrict__ E,
                                                float* __restrict__ invn,
                                                float* __restrict__ PS0,
                                                float* __restrict__ R0,
                                                unsigned* __restrict__ cnt) {
    __shared__ float fbuf[2][4096];  // [row 0..63][col 0..63], swizzled-by-source
    __shared__ float bsr[4][KC];
    __shared__ int lastblk;
    int tid = threadIdx.x;
    int wave = tid >> 6, lane = tid & 63;
    int l15 = lane & 15, lhi = lane >> 4;
    int rowbase = blockIdx.x * 64;

    int srow = tid >> 4;       // staging row 0..15 (+16 per issue)
    int c4 = (tid & 15) * 4;   // staging col group

    f32x4 acc[4];
#pragma unroll
    for (int n = 0; n < 4; ++n) acc[n] = (f32x4){0.f, 0.f, 0.f, 0.f};
    float ss = 0.f;

    auto stage = [&](int t, int b) {
#pragma unroll
        for (int i = 0; i < 4; ++i) {
            int row = i * 16 + srow;
            const float* src = F + (size_t)(rowbase + row) * DIM + t * 64 + (c4 ^ ((row & 7) << 2));
            float* dst = &fbuf[b][i * 1024 + wave * 256];  // wave-uniform; HW adds lane*16B
            __builtin_amdgcn_global_load_lds((const __attribute__((address_space(1))) void*)src,
                                             (__attribute__((address_space(3))) void*)dst, 16, 0, 0);
        }
    };

    stage(0, 0);
    __syncthreads();

    int myrow = wave * 16 + l15;
    int swz = (l15 & 7) << 2;
    const short* Bb = cnbf + (size_t)l15 * DIM + lhi * 8;

    for (int t = 0; t < 12; ++t) {
        int cur = t & 1;
        if (t < 11) stage(t + 1, cur ^ 1);  // in flight during compute below
        const float* cb = fbuf[cur] + myrow * 64;
#pragma unroll
        for (int kk = 0; kk < 64; kk += 32) {
            int c0s = (kk + lhi * 8) ^ swz;
            f32x4 fa = *(const f32x4*)(cb + c0s);
            f32x4 fb2 = *(const f32x4*)(cb + (c0s ^ 4));
            ss += fa[0] * fa[0] + fa[1] * fa[1] + fa[2] * fa[2] + fa[3] * fa[3]
                + fb2[0] * fb2[0] + fb2[1] * fb2[1] + fb2[2] * fb2[2] + fb2[3] * fb2[3];
            bf16x8 af;
            af[0] = f2bf(fa[0]); af[1] = f2bf(fa[1]); af[2] = f2bf(fa[2]); af[3] = f2bf(fa[3]);
            af[4] = f2bf(fb2[0]); af[5] = f2bf(fb2[1]); af[6] = f2bf(fb2[2]); af[7] = f2bf(fb2[3]);
#pragma unroll
            for (int n = 0; n < 4; ++n) {
                bf16x8 b = *(const bf16x8*)(Bb + (size_t)n * 16 * DIM + t * 64 + kk);
                acc[n] = __builtin_amdgcn_mfma_f32_16x16x32_bf16(af, b, acc[n], 0, 0, 0);
            }
        }
        __syncthreads();
    }

    // ---- per-wave epilogue ----
    ss += __shfl_xor(ss, 16);
    ss += __shfl_xor(ss, 32);
    float inv = 1.0f / fmaxf(sqrtf(ss), 1e-12f);
    int growbase = rowbase + wave * 16;
    if (lane < 16) invn[growbase + lane] = inv;

    float sc[4];
#pragma unroll
    for (int j = 0; j < 4; ++j) sc[j] = __shfl(inv, lhi * 4 + j) * INV_T;

    float colp[4] = {0.f, 0.f, 0.f, 0.f};
#pragma unroll
    for (int n = 0; n < 4; ++n) {
#pragma unroll
        for (int j = 0; j < 4; ++j) {
            float e = expf(acc[n][j] * sc[j]);
            int row = lhi * 4 + j;  // row & 15
            E[(size_t)(growbase + row) * KC + ((n * 16 + l15) ^ (row << 2))] = e;
            colp[n] += e;
        }
    }
#pragma unroll
    for (int n = 0; n < 4; ++n) {
        colp[n] += __shfl_xor(colp[n], 16);
        colp[n] += __shfl_xor(colp[n], 32);
    }
    if (lane < 16) {
#pragma unroll
        for (int n = 0; n < 4; ++n) bsr[wave][n * 16 + lane] = colp[n];
    }
    __syncthreads();
    if (tid < KC) PS0[(size_t)blockIdx.x * KC + tid] =
        bsr[0][tid] + bsr[1][tid] + bsr[2][tid] + bsr[3][tid];

    // ---- last-block epilogue: PS0 -> R0 ----
    __threadfence();
    __syncthreads();
    if (tid == 0) lastblk = (atomicAdd(cnt, 1u) == (unsigned)(gridDim.x - 1));
    __syncthreads();
    if (!lastblk) return;
    __threadfence();
    int k = tid & 63, g = tid >> 6;
    float s = 0.f;
    for (int p = g; p < LOGITS_BLOCKS; p += 4) s += PS0[(size_t)p * KC + k];
    bsr[g][k] = s;
    __syncthreads();
    if (tid < KC) {
        float sk = bsr[0][k] + bsr[1][k] + bsr[2][k] + bsr[3][k];
        float tot = sk;
        for (int o = 32; o; o >>= 1) tot += __shfl_xor(tot, o);
        float S = fmaxf(tot, 1e-12f);
        R0[k] = (1.0f / S) / (fmaxf(sk / S, 1e-12f) * 64.0f);
    }
}

// ---------------- P: sink pass, shuffle-free (LDS transpose reduction) ------------
// E tile (pre-swizzled, 128x64) staged via global_load_lds; prescaled by R[k];
// row sums by thread-per-row serial LDS reads; lane=k phase writes c/A/Qbf.
// MODE 0/1 end with last-block epilogue computing Rout; MODE 2 writes A/Qbf/PSM.
template <int MODE>
__global__ __launch_bounds__(256) void k_sink(const float* __restrict__ E,
                                              const float* __restrict__ R,
                                              const float* __restrict__ invn,
                                              float* __restrict__ c,
                                              float* __restrict__ PS,
                                              float* __restrict__ Aout,
                                              short* __restrict__ Qbf,
                                              float* __restrict__ Rout,
                                              unsigned* __restrict__ cnt) {
    __shared__ float tile[SROWS * KC];  // 32 KiB
    __shared__ float sbuf[SROWS];
    __shared__ float Rlds[KC];
    __shared__ float bacc[4][KC];
    __shared__ int lastblk;
    int tid = threadIdx.x, lane = tid & 63, wave = tid >> 6;
    int m0 = blockIdx.x * SROWS;

    if (tid < KC) Rlds[tid] = R[tid];

    // phase 1: stage E rows (memory layout already swizzled -> linear copy)
#pragma unroll
    for (int i = 0; i < 8; ++i) {
        const float* src = E + (size_t)(m0 + i * 16 + wave * 4 + (lane >> 4)) * KC + (lane & 15) * 4;
        float* dst = tile + (i * 16 + wave * 4) * KC;
        __builtin_amdgcn_global_load_lds((const __attribute__((address_space(1))) void*)src,
                                         (__attribute__((address_space(3))) void*)dst, 16, 0, 0);
    }
    __syncthreads();

    // phase 1.5: v = e * R[k]   (k = col ^ swizzle(row))
#pragma unroll
    for (int i = 0; i < 32; ++i) {
        int idx = tid + i * 256;
        int mloc = idx >> 6, ccol = idx & 63;
        tile[idx] *= Rlds[ccol ^ ((mloc & 15) << 2)];
    }
    __syncthreads();

    // phase 2: row sums of v (thread-per-row, XOR-ordered reads)
    if (tid < SROWS) {
        const float* rp = tile + tid * KC;
        int sw = tid & 15;
        f32x4 a0 = {0.f, 0.f, 0.f, 0.f}, a1 = {0.f, 0.f, 0.f, 0.f};
#pragma unroll
        for (int j = 0; j < 16; j += 2) {
            a0 += *(const f32x4*)(rp + ((j ^ sw) << 2));
            a1 += *(const f32x4*)(rp + (((j + 1) ^ sw) << 2));
        }
        f32x4 a = a0 + a1;
        sbuf[tid] = a[0] + a[1] + a[2] + a[3];
    }
    __syncthreads();

    // phase 3: lane = k; 32 rows per wave
    float wacc = 0.f;
    int rbase = wave * 32;
#pragma unroll 4
    for (int r = 0; r < 32; ++r) {
        int rr = rbase + r;
        int m = m0 + rr;
        float v = tile[rr * KC + (lane ^ ((rr & 15) << 2))];
        float s = sbuf[rr];
        float cold = (MODE == 0) ? 1.0f : c[m];
        float cnew = cold / (fmaxf(cold * s, 1e-12f) * 65536.0f);
        if (MODE == 2) {
            float a = v * cnew * 65536.0f;
            size_t idx = (size_t)m * KC + lane;
            Aout[idx] = a;
            Qbf[idx] = f2bf(a * invn[m]);
            wacc += a;
        } else {
            if (lane == 0) c[m] = cnew;
            wacc += v * cnew;  // = (e*R)*cnew ; divided by R[k] below
        }
    }
    bacc[wave][lane] = wacc;
    __syncthreads();
    if (tid < KC) {
        float ps = bacc[0][tid] + bacc[1][tid] + bacc[2][tid] + bacc[3][tid];
        if (MODE != 2) ps /= Rlds[tid];
        PS[(size_t)blockIdx.x * KC + tid] = ps;
    }
    if (MODE == 2) return;

    // last-block epilogue: PS -> Rout
    __threadfence();
    __syncthreads();
    if (tid == 0) lastblk = (atomicAdd(cnt, 1u) == (unsigned)(gridDim.x - 1));
    __syncthreads();
    if (!lastblk) return;
    __threadfence();
    int k = tid & 63, g = tid >> 6;
    float s = 0.f;
    for (int p = g; p < SINK_BLOCKS; p += 4) s += PS[(size_t)p * KC + k];
    bacc[g][k] = s;
    __syncthreads();
    if (tid < KC) {
        float sk = bacc[0][k] + bacc[1][k] + bacc[2][k] + bacc[3][k];
        float r = Rlds[k];
        Rout[k] = r / (fmaxf(r * sk, 1e-12f) * 64.0f);
    }
}

// ---------------- K3: weighted centers — bf16 MFMA GEMM, prefetched ---------------
__global__ __launch_bounds__(256) void k_weighted(const float* __restrict__ F,
                                                  const short* __restrict__ Qbf,
                                                  float* __restrict__ P) {
    __shared__ short ldsF[DT * MB];  // [d][m] swizzled, 16 KiB
    __shared__ short ldsQ[KC * MB];  // [k][m] swizzled, 8 KiB
    int tid = threadIdx.x;
    int dt = blockIdx.x;  // 0..5
    int ms = blockIdx.y;  // 0..MSEG-1
    int wave = tid >> 6, lane = tid & 63;
    int l15 = lane & 15, lhi = lane >> 4;

    int m0 = ms * (MB * CH);
    int d0 = dt * DT;

    f32x4 acc[4][2];
#pragma unroll
    for (int kt = 0; kt < 4; ++kt)
#pragma unroll
        for (int ds = 0; ds < 2; ++ds) acc[kt][ds] = (f32x4){0.f, 0.f, 0.f, 0.f};

    int f_dq = (tid & 31) * 4;        // d 0..124 (float4 loads)
    int f_m8 = (tid >> 5) * 8;        // m 0..56
    int q_kq = (tid & 15) * 4;        // k 0..60   (threads <128)
    int q_m8 = ((tid >> 4) & 7) * 8;  // m 0..56

    float4 rf[8];
    u16x4 q[8];
#define LOADCH(mb_)                                                                       \
    do {                                                                                  \
        _Pragma("unroll") for (int j = 0; j < 8; ++j)                                     \
            rf[j] = *(const float4*)(F + (size_t)((mb_) + f_m8 + j) * DIM + d0 + f_dq);   \
        if (tid < 128) {                                                                  \
            _Pragma("unroll") for (int j = 0; j < 8; ++j)                                 \
                q[j] = *(const u16x4*)(Qbf + (size_t)((mb_) + q_m8 + j) * KC + q_kq);     \
        }                                                                                 \
    } while (0)

    LOADCH(m0);
    for (int ch = 0; ch < CH; ++ch) {
        __syncthreads();  // previous chunk's LDS reads done before overwrite
#pragma unroll
        for (int i = 0; i < 4; ++i) {
            int d = f_dq + i;
            uint4 w;
            w.x = (unsigned)(unsigned short)f2bf(rf[0][i]) | ((unsigned)(unsigned short)f2bf(rf[1][i]) << 16);
            w.y = (unsigned)(unsigned short)f2bf(rf[2][i]) | ((unsigned)(unsigned short)f2bf(rf[3][i]) << 16);
            w.z = (unsigned)(unsigned short)f2bf(rf[4][i]) | ((unsigned)(unsigned short)f2bf(rf[5][i]) << 16);
            w.w = (unsigned)(unsigned short)f2bf(rf[6][i]) | ((unsigned)(unsigned short)f2bf(rf[7][i]) << 16);
            int byte = (d * (MB * 2) + f_m8 * 2) ^ ((d & 7) << 4);
            *(uint4*)((char*)ldsF + byte) = w;
        }
        if (tid < 128) {
#pragma unroll
            for (int i = 0; i < 4; ++i) {
                int k = q_kq + i;
                uint4 w;
                w.x = (unsigned)q[0][i] | ((unsigned)q[1][i] << 16);
                w.y = (unsigned)q[2][i] | ((unsigned)q[3][i] << 16);
                w.z = (unsigned)q[4][i] | ((unsigned)q[5][i] << 16);
                w.w = (unsigned)q[6][i] | ((unsigned)q[7][i] << 16);
                int byte = (k * (MB * 2) + q_m8 * 2) ^ ((k & 7) << 4);
                *(uint4*)((char*)ldsQ + byte) = w;
            }
        }
        __syncthreads();
        if (ch + 1 < CH) LOADCH(m0 + (ch + 1) * MB);  // prefetch overlaps MFMA below
#pragma unroll
        for (int h = 0; h < 2; ++h) {
            bf16x8 afr[4];
#pragma unroll
            for (int kt = 0; kt < 4; ++kt) {
                int k = kt * 16 + l15;
                int byte = (k * (MB * 2) + (h * 32 + lhi * 8) * 2) ^ ((k & 7) << 4);
                afr[kt] = *(bf16x8*)((char*)ldsQ + byte);
            }
#pragma unroll
            for (int ds = 0; ds < 2; ++ds) {
                int d = wave * 32 + ds * 16 + l15;
                int byte = (d * (MB * 2) + (h * 32 + lhi * 8) * 2) ^ ((d & 7) << 4);
                bf16x8 bfr = *(bf16x8*)((char*)ldsF + byte);
#pragma unroll
                for (int kt = 0; kt < 4; ++kt)
                    acc[kt][ds] = __builtin_amdgcn_mfma_f32_16x16x32_bf16(afr[kt], bfr, acc[kt][ds], 0, 0, 0);
            }
        }
    }
#undef LOADCH

    float* Pb = P + (size_t)ms * (KC * DIM) + d0;
#pragma unroll
    for (int kt = 0; kt < 4; ++kt)
#pragma unroll
        for (int ds = 0; ds < 2; ++ds) {
            int d = wave * 32 + ds * 16 + l15;
#pragma unroll
            for (int r4 = 0; r4 < 4; ++r4) {
                int k = kt * 16 + lhi * 4 + r4;
                Pb[(size_t)k * DIM + d] = acc[kt][ds][r4];
            }
        }
}

// ---------------- R2: reduce the MSEG partials -> weighted ------------------------
__global__ __launch_bounds__(128) void k_reducep(const float* __restrict__ P,
                                                 float* __restrict__ W) {
    int o = blockIdx.x * 128 + threadIdx.x;  // 0..49151
    const float* p = P + o;
    float s0 = 0.f, s1 = 0.f, s2 = 0.f, s3 = 0.f;
    size_t stride = (size_t)KC * DIM;
#pragma unroll 4
    for (int g = 0; g < MSEG; g += 4) {
        s0 += p[(size_t)g * stride];
        s1 += p[(size_t)(g + 1) * stride];
        s2 += p[(size_t)(g + 2) * stride];
        s3 += p[(size_t)(g + 3) * stride];
    }
    W[o] = (s0 + s1) + (s2 + s3);
}

// ---------------- K4: mass-reduce + finalize centers ------------------------------
__global__ __launch_bounds__(256) void k_final(const float* __restrict__ W,
                                               const float* __restrict__ PSM,
                                               const float* __restrict__ cn,
                                               float* __restrict__ outC) {
    int k = blockIdx.x, tid = threadIdx.x;
    __shared__ float red[4];

    float msum = 0.f;
    for (int p = tid; p < SINK_BLOCKS; p += 256) msum += PSM[(size_t)p * KC + k];
    for (int o = 32; o; o >>= 1) msum += __shfl_xor(msum, o);
    if ((tid & 63) == 0) red[tid >> 6] = msum;
    __syncthreads();
    float mk = fmaxf(red[0] + red[1] + red[2] + red[3], 1e-6f);
    __syncthreads();

    float w[3];
#pragma unroll
    for (int g = 0; g < 3; ++g) w[g] = W[k * DIM + tid + g * 256] / mk;

    float ss = w[0] * w[0] + w[1] * w[1] + w[2] * w[2];
    for (int o = 32; o; o >>= 1) ss += __shfl_xor(ss, o);
    if ((tid & 63) == 0) red[tid >> 6] = ss;
    __syncthreads();
    ss = red[0] + red[1] + red[2] + red[3];
    float n1 = fmaxf(sqrtf(ss), 1e-12f);
    __syncthreads();

    float u0 = 0.99f * cn[k * DIM + tid]       + 0.01f * (w[0] / n1);
    float u1 = 0.99f * cn[k * DIM + tid + 256] + 0.01f * (w[1] / n1);
    float u2 = 0.99f * cn[k * DIM + tid + 512] + 0.01f * (w[2] / n1);
    float ss2 = u0 * u0 + u1 * u1 + u2 * u2;
    for (int o = 32; o; o >>= 1) ss2 += __shfl_xor(ss2, o);
    if ((tid & 63) == 0) red[tid >> 6] = ss2;
    __syncthreads();
    ss2 = red[0] + red[1] + red[2] + red[3];
    float n2 = fmaxf(sqrtf(ss2), 1e-12f);

    outC[k * DIM + tid]       = u0 / n2;
    outC[k * DIM + tid + 256] = u1 / n2;
    outC[k * DIM + tid + 512] = u2 / n2;
}

extern "C" void kernel_launch(void* const* d_in, const int* in_sizes, int n_in,
                              void* d_out, int out_size, void* d_ws, size_t ws_size,
                              hipStream_t stream) {
    const float* F = (const float*)d_in[0];        // [65536][768]
    const float* centers = (const float*)d_in[1];  // [64][768]
    float* out = (float*)d_out;
    float* A = out;                                 // assignments [65536][64]
    float* outC = out + (size_t)M_TOTAL * KC;       // updated centers [64][768]

    float* w = (float*)d_ws;                        // ws = 768 MiB
    float* cn   = w;                                // 49152
    short* cnbf = (short*)(w + 49152);              // 24576 float slots
    float* R0   = w + 73728;                        // 64
    float* R1   = w + 73792;                        // 64
    float* R2   = w + 73856;                        // 64
    unsigned* cnt = (unsigned*)(w + 73920);         // 3 counters (zeroed by k_centers)
    float* invn = w + 74048;                        // 65536
    float* cbuf = w + 139584;                       // 65536
    float* E    = w + 205120;                       // 4194304 (pre-swizzled layout)
    short* Qbf  = (short*)(w + 4399424);            // 2097152 float slots (8 MiB)
    float* PS0  = w + 6496576;                      // 1024*64
    float* PS1  = w + 6562112;                      // 512*64
    float* PS2  = w + 6594880;                      // 512*64
    float* PSM  = w + 6627648;                      // 512*64
    float* partial = w + 6660416;                   // MSEG*64*768 = 6291456 (24 MiB)
    float* weighted = w + 12951872;                 // 49152

    k_centers<<<KC, 256, 0, stream>>>(centers, cn, cnbf, cnt);
    k_logits<<<LOGITS_BLOCKS, 256, 0, stream>>>(F, cnbf, E, invn, PS0, R0, cnt);
    k_sink<0><<<SINK_BLOCKS, 256, 0, stream>>>(E, R0, invn, cbuf, PS1, A, Qbf, R1, cnt + 1);
    k_sink<1><<<SINK_BLOCKS, 256, 0, stream>>>(E, R1, invn, cbuf, PS2, A, Qbf, R2, cnt + 2);
    k_sink<2><<<SINK_BLOCKS, 256, 0, stream>>>(E, R2, invn, cbuf, PSM, A, Qbf, nullptr, nullptr);

    dim3 wgrid(DIM / DT, MSEG);
    k_weighted<<<wgrid, 256, 0, stream>>>(F, Qbf, partial);
    k_reducep<<<(KC * DIM) / 128, 128, 0, stream>>>(partial, weighted);
    k_final<<<KC, 256, 0, stream>>>(weighted, PSM, cn, outC);
}

// Round 8
// 193.764 us; speedup vs baseline: 2.3996x; 2.3996x over previous
//
#include <hip/hip_runtime.h>
#include <hip/hip_bf16.h>

#define M_TOTAL 65536
#define DIM 768
#define KC 64
#define INV_T 10.0f

// k_weighted tiling
#define DT 128    // d-cols per block
#define MB 64     // m per LDS chunk
#define CH 8      // chunks per block (m-range 512)
#define MSEG 128  // m-segments (partials)

#define LOGITS_BLOCKS (M_TOTAL / 64)   // 1024 (64 rows per block)
#define SROWS 128
#define SINK_BLOCKS (M_TOTAL / SROWS)  // 512

typedef __attribute__((ext_vector_type(4))) float f32x4;
typedef __attribute__((ext_vector_type(8))) short bf16x8;
typedef __attribute__((ext_vector_type(4))) unsigned short u16x4;

__device__ __forceinline__ short f2bf(float f) {
    __hip_bfloat16 h = __float2bfloat16(f);
    union { __hip_bfloat16 h; short s; } u; u.h = h;
    return u.s;
}

// ---------------- K0: normalize centers -> cn (fp32) + cnbf (bf16) ----------------
__global__ __launch_bounds__(256) void k_centers(const float* __restrict__ centers,
                                                 float* __restrict__ cn,
                                                 short* __restrict__ cnbf) {
    int k = blockIdx.x, tid = threadIdx.x;
    float ss = 0.f;
    for (int i = tid; i < DIM; i += 256) { float v = centers[k * DIM + i]; ss += v * v; }
    __shared__ float red[4];
    for (int o = 32; o; o >>= 1) ss += __shfl_xor(ss, o);
    if ((tid & 63) == 0) red[tid >> 6] = ss;
    __syncthreads();
    ss = red[0] + red[1] + red[2] + red[3];
    float inv = 1.0f / fmaxf(sqrtf(ss), 1e-12f);
    for (int i = tid; i < DIM; i += 256) {
        float v = centers[k * DIM + i] * inv;
        cn[k * DIM + i] = v;
        cnbf[k * DIM + i] = f2bf(v);
    }
}

// ---------------- K1: logits GEMM (staged) + exp -> E (pre-swizzled), invn, PS0 ---
// E storage: E[m][c] holds E_true[m][c ^ ((m&15)<<2)] (bijective within row; only
// k_sink reads E and knows the layout). NO device-scope fences (R7 lesson: each
// __threadfence() on gfx950 = L2 writeback x grid -> +170us). Reduction in k_redR.
__global__ __launch_bounds__(256) void k_logits(const float* __restrict__ F,
                                                const short* __restrict__ cnbf,
                                                float* __restrict__ E,
                                                float* __restrict__ invn,
                                                float* __restrict__ PS0) {
    __shared__ float fbuf[2][4096];  // [row 0..63][col 0..63], swizzled-by-source
    __shared__ float bsr[4][KC];
    int tid = threadIdx.x;
    int wave = tid >> 6, lane = tid & 63;
    int l15 = lane & 15, lhi = lane >> 4;
    int rowbase = blockIdx.x * 64;

    int srow = tid >> 4;       // staging row 0..15 (+16 per issue)
    int c4 = (tid & 15) * 4;   // staging col group

    f32x4 acc[4];
#pragma unroll
    for (int n = 0; n < 4; ++n) acc[n] = (f32x4){0.f, 0.f, 0.f, 0.f};
    float ss = 0.f;

    auto stage = [&](int t, int b) {
#pragma unroll
        for (int i = 0; i < 4; ++i) {
            int row = i * 16 + srow;
            const float* src = F + (size_t)(rowbase + row) * DIM + t * 64 + (c4 ^ ((row & 7) << 2));
            float* dst = &fbuf[b][i * 1024 + wave * 256];  // wave-uniform; HW adds lane*16B
            __builtin_amdgcn_global_load_lds((const __attribute__((address_space(1))) void*)src,
                                             (__attribute__((address_space(3))) void*)dst, 16, 0, 0);
        }
    };

    stage(0, 0);
    __syncthreads();

    int myrow = wave * 16 + l15;
    int swz = (l15 & 7) << 2;
    const short* Bb = cnbf + (size_t)l15 * DIM + lhi * 8;

    for (int t = 0; t < 12; ++t) {
        int cur = t & 1;
        if (t < 11) stage(t + 1, cur ^ 1);  // in flight during compute below
        const float* cb = fbuf[cur] + myrow * 64;
#pragma unroll
        for (int kk = 0; kk < 64; kk += 32) {
            int c0s = (kk + lhi * 8) ^ swz;
            f32x4 fa = *(const f32x4*)(cb + c0s);
            f32x4 fb2 = *(const f32x4*)(cb + (c0s ^ 4));
            ss += fa[0] * fa[0] + fa[1] * fa[1] + fa[2] * fa[2] + fa[3] * fa[3]
                + fb2[0] * fb2[0] + fb2[1] * fb2[1] + fb2[2] * fb2[2] + fb2[3] * fb2[3];
            bf16x8 af;
            af[0] = f2bf(fa[0]); af[1] = f2bf(fa[1]); af[2] = f2bf(fa[2]); af[3] = f2bf(fa[3]);
            af[4] = f2bf(fb2[0]); af[5] = f2bf(fb2[1]); af[6] = f2bf(fb2[2]); af[7] = f2bf(fb2[3]);
#pragma unroll
            for (int n = 0; n < 4; ++n) {
                bf16x8 b = *(const bf16x8*)(Bb + (size_t)n * 16 * DIM + t * 64 + kk);
                acc[n] = __builtin_amdgcn_mfma_f32_16x16x32_bf16(af, b, acc[n], 0, 0, 0);
            }
        }
        __syncthreads();
    }

    // ---- per-wave epilogue ----
    ss += __shfl_xor(ss, 16);
    ss += __shfl_xor(ss, 32);
    float inv = 1.0f / fmaxf(sqrtf(ss), 1e-12f);
    int growbase = rowbase + wave * 16;
    if (lane < 16) invn[growbase + lane] = inv;

    float sc[4];
#pragma unroll
    for (int j = 0; j < 4; ++j) sc[j] = __shfl(inv, lhi * 4 + j) * INV_T;

    float colp[4] = {0.f, 0.f, 0.f, 0.f};
#pragma unroll
    for (int n = 0; n < 4; ++n) {
#pragma unroll
        for (int j = 0; j < 4; ++j) {
            float e = expf(acc[n][j] * sc[j]);
            int row = lhi * 4 + j;  // row & 15
            E[(size_t)(growbase + row) * KC + ((n * 16 + l15) ^ (row << 2))] = e;
            colp[n] += e;
        }
    }
#pragma unroll
    for (int n = 0; n < 4; ++n) {
        colp[n] += __shfl_xor(colp[n], 16);
        colp[n] += __shfl_xor(colp[n], 32);
    }
    if (lane < 16) {
#pragma unroll
        for (int n = 0; n < 4; ++n) bsr[wave][n * 16 + lane] = colp[n];
    }
    __syncthreads();
    if (tid < KC) PS0[(size_t)blockIdx.x * KC + tid] =
        bsr[0][tid] + bsr[1][tid] + bsr[2][tid] + bsr[3][tid];
}

// ---------------- k_redR: reduce per-block partials + compute R scale -------------
template <int STAGE>
__global__ __launch_bounds__(1024) void k_redR(const float* __restrict__ PS, int nblocks,
                                               const float* __restrict__ Rin,
                                               float* __restrict__ Rout) {
    __shared__ float part[16][KC];
    int k = threadIdx.x & 63, g = threadIdx.x >> 6;
    float s = 0.f;
    for (int p = g; p < nblocks; p += 16) s += PS[(size_t)p * KC + k];
    part[g][k] = s;
    __syncthreads();
    if (threadIdx.x < KC) {
        float sk = 0.f;
#pragma unroll
        for (int g2 = 0; g2 < 16; ++g2) sk += part[g2][k];
        if (STAGE == 0) {
            float tot = sk;
            for (int o = 32; o; o >>= 1) tot += __shfl_xor(tot, o);
            float S = fmaxf(tot, 1e-12f);
            Rout[k] = (1.0f / S) / (fmaxf(sk / S, 1e-12f) * 64.0f);
        } else {
            float r = Rin[k];
            Rout[k] = r / (fmaxf(r * sk, 1e-12f) * 64.0f);
        }
    }
}

// ---------------- P: sink pass, shuffle-free (LDS-based row sums) -----------------
// E tile (pre-swizzled, 128x64) staged via global_load_lds; prescaled by R[k];
// row sums by thread-per-row vector LDS reads; lane=k phase writes c/A/Qbf.
template <int MODE>
__global__ __launch_bounds__(256) void k_sink(const float* __restrict__ E,
                                              const float* __restrict__ R,
                                              const float* __restrict__ invn,
                                              float* __restrict__ c,
                                              float* __restrict__ PS,
                                              float* __restrict__ Aout,
                                              short* __restrict__ Qbf) {
    __shared__ float tile[SROWS * KC];  // 32 KiB
    __shared__ float sbuf[SROWS];
    __shared__ float Rlds[KC];
    __shared__ float bacc[4][KC];
    int tid = threadIdx.x, lane = tid & 63, wave = tid >> 6;
    int m0 = blockIdx.x * SROWS;

    if (tid < KC) Rlds[tid] = R[tid];

    // phase 1: stage E rows (memory layout already swizzled -> linear copy)
#pragma unroll
    for (int i = 0; i < 8; ++i) {
        const float* src = E + (size_t)(m0 + i * 16 + wave * 4 + (lane >> 4)) * KC + (lane & 15) * 4;
        float* dst = tile + (i * 16 + wave * 4) * KC;
        __builtin_amdgcn_global_load_lds((const __attribute__((address_space(1))) void*)src,
                                         (__attribute__((address_space(3))) void*)dst, 16, 0, 0);
    }
    __syncthreads();

    // phase 1.5: v = e * R[k]   (k = col ^ swizzle(row))
#pragma unroll
    for (int i = 0; i < 32; ++i) {
        int idx = tid + i * 256;
        int mloc = idx >> 6, ccol = idx & 63;
        tile[idx] *= Rlds[ccol ^ ((mloc & 15) << 2)];
    }
    __syncthreads();

    // phase 2: row sums of v (thread-per-row, XOR-ordered vector reads)
    if (tid < SROWS) {
        const float* rp = tile + tid * KC;
        int sw = tid & 15;
        f32x4 a0 = {0.f, 0.f, 0.f, 0.f}, a1 = {0.f, 0.f, 0.f, 0.f};
#pragma unroll
        for (int j = 0; j < 16; j += 2) {
            a0 += *(const f32x4*)(rp + ((j ^ sw) << 2));
            a1 += *(const f32x4*)(rp + (((j + 1) ^ sw) << 2));
        }
        f32x4 a = a0 + a1;
        sbuf[tid] = a[0] + a[1] + a[2] + a[3];
    }
    __syncthreads();

    // phase 3: lane = k; 32 rows per wave
    float wacc = 0.f;
    int rbase = wave * 32;
#pragma unroll 4
    for (int r = 0; r < 32; ++r) {
        int rr = rbase + r;
        int m = m0 + rr;
        float v = tile[rr * KC + (lane ^ ((rr & 15) << 2))];
        float s = sbuf[rr];
        float cold = (MODE == 0) ? 1.0f : c[m];
        float cnew = cold / (fmaxf(cold * s, 1e-12f) * 65536.0f);
        if (MODE == 2) {
            float a = v * cnew * 65536.0f;
            size_t idx = (size_t)m * KC + lane;
            Aout[idx] = a;
            Qbf[idx] = f2bf(a * invn[m]);
            wacc += a;
        } else {
            if (lane == 0) c[m] = cnew;
            wacc += v * cnew;  // = (e*R)*cnew ; divided by R[k] below
        }
    }
    bacc[wave][lane] = wacc;
    __syncthreads();
    if (tid < KC) {
        float ps = bacc[0][tid] + bacc[1][tid] + bacc[2][tid] + bacc[3][tid];
        if (MODE != 2) ps /= Rlds[tid];
        PS[(size_t)blockIdx.x * KC + tid] = ps;
    }
}

// ---------------- K3: weighted centers — bf16 MFMA GEMM, prefetched ---------------
__global__ __launch_bounds__(256) void k_weighted(const float* __restrict__ F,
                                                  const short* __restrict__ Qbf,
                                                  float* __restrict__ P) {
    __shared__ short ldsF[DT * MB];  // [d][m] swizzled, 16 KiB
    __shared__ short ldsQ[KC * MB];  // [k][m] swizzled, 8 KiB
    int tid = threadIdx.x;
    int dt = blockIdx.x;  // 0..5
    int ms = blockIdx.y;  // 0..MSEG-1
    int wave = tid >> 6, lane = tid & 63;
    int l15 = lane & 15, lhi = lane >> 4;

    int m0 = ms * (MB * CH);
    int d0 = dt * DT;

    f32x4 acc[4][2];
#pragma unroll
    for (int kt = 0; kt < 4; ++kt)
#pragma unroll
        for (int ds = 0; ds < 2; ++ds) acc[kt][ds] = (f32x4){0.f, 0.f, 0.f, 0.f};

    int f_dq = (tid & 31) * 4;        // d 0..124 (float4 loads)
    int f_m8 = (tid >> 5) * 8;        // m 0..56
    int q_kq = (tid & 15) * 4;        // k 0..60   (threads <128)
    int q_m8 = ((tid >> 4) & 7) * 8;  // m 0..56

    float4 rf[8];
    u16x4 q[8];
#define LOADCH(mb_)                                                                       \
    do {                                                                                  \
        _Pragma("unroll") for (int j = 0; j < 8; ++j)                                     \
            rf[j] = *(const float4*)(F + (size_t)((mb_) + f_m8 + j) * DIM + d0 + f_dq);   \
        if (tid < 128) {                                                                  \
            _Pragma("unroll") for (int j = 0; j < 8; ++j)                                 \
                q[j] = *(const u16x4*)(Qbf + (size_t)((mb_) + q_m8 + j) * KC + q_kq);     \
        }                                                                                 \
    } while (0)

    LOADCH(m0);
    for (int ch = 0; ch < CH; ++ch) {
        __syncthreads();  // previous chunk's LDS reads done before overwrite
#pragma unroll
        for (int i = 0; i < 4; ++i) {
            int d = f_dq + i;
            uint4 w;
            w.x = (unsigned)(unsigned short)f2bf(rf[0][i]) | ((unsigned)(unsigned short)f2bf(rf[1][i]) << 16);
            w.y = (unsigned)(unsigned short)f2bf(rf[2][i]) | ((unsigned)(unsigned short)f2bf(rf[3][i]) << 16);
            w.z = (unsigned)(unsigned short)f2bf(rf[4][i]) | ((unsigned)(unsigned short)f2bf(rf[5][i]) << 16);
            w.w = (unsigned)(unsigned short)f2bf(rf[6][i]) | ((unsigned)(unsigned short)f2bf(rf[7][i]) << 16);
            int byte = (d * (MB * 2) + f_m8 * 2) ^ ((d & 7) << 4);
            *(uint4*)((char*)ldsF + byte) = w;
        }
        if (tid < 128) {
#pragma unroll
            for (int i = 0; i < 4; ++i) {
                int k = q_kq + i;
                uint4 w;
                w.x = (unsigned)q[0][i] | ((unsigned)q[1][i] << 16);
                w.y = (unsigned)q[2][i] | ((unsigned)q[3][i] << 16);
                w.z = (unsigned)q[4][i] | ((unsigned)q[5][i] << 16);
                w.w = (unsigned)q[6][i] | ((unsigned)q[7][i] << 16);
                int byte = (k * (MB * 2) + q_m8 * 2) ^ ((k & 7) << 4);
                *(uint4*)((char*)ldsQ + byte) = w;
            }
        }
        __syncthreads();
        if (ch + 1 < CH) LOADCH(m0 + (ch + 1) * MB);  // prefetch overlaps MFMA below
#pragma unroll
        for (int h = 0; h < 2; ++h) {
            bf16x8 afr[4];
#pragma unroll
            for (int kt = 0; kt < 4; ++kt) {
                int k = kt * 16 + l15;
                int byte = (k * (MB * 2) + (h * 32 + lhi * 8) * 2) ^ ((k & 7) << 4);
                afr[kt] = *(bf16x8*)((char*)ldsQ + byte);
            }
#pragma unroll
            for (int ds = 0; ds < 2; ++ds) {
                int d = wave * 32 + ds * 16 + l15;
                int byte = (d * (MB * 2) + (h * 32 + lhi * 8) * 2) ^ ((d & 7) << 4);
                bf16x8 bfr = *(bf16x8*)((char*)ldsF + byte);
#pragma unroll
                for (int kt = 0; kt < 4; ++kt)
                    acc[kt][ds] = __builtin_amdgcn_mfma_f32_16x16x32_bf16(afr[kt], bfr, acc[kt][ds], 0, 0, 0);
            }
        }
    }
#undef LOADCH

    float* Pb = P + (size_t)ms * (KC * DIM) + d0;
#pragma unroll
    for (int kt = 0; kt < 4; ++kt)
#pragma unroll
        for (int ds = 0; ds < 2; ++ds) {
            int d = wave * 32 + ds * 16 + l15;
#pragma unroll
            for (int r4 = 0; r4 < 4; ++r4) {
                int k = kt * 16 + lhi * 4 + r4;
                Pb[(size_t)k * DIM + d] = acc[kt][ds][r4];
            }
        }
}

// ---------------- R2: reduce the MSEG partials -> weighted ------------------------
__global__ __launch_bounds__(128) void k_reducep(const float* __restrict__ P,
                                                 float* __restrict__ W) {
    int o = blockIdx.x * 128 + threadIdx.x;  // 0..49151
    const float* p = P + o;
    float s0 = 0.f, s1 = 0.f, s2 = 0.f, s3 = 0.f;
    size_t stride = (size_t)KC * DIM;
#pragma unroll 4
    for (int g = 0; g < MSEG; g += 4) {
        s0 += p[(size_t)g * stride];
        s1 += p[(size_t)(g + 1) * stride];
        s2 += p[(size_t)(g + 2) * stride];
        s3 += p[(size_t)(g + 3) * stride];
    }
    W[o] = (s0 + s1) + (s2 + s3);
}

// ---------------- K4: mass-reduce + finalize centers ------------------------------
__global__ __launch_bounds__(256) void k_final(const float* __restrict__ W,
                                               const float* __restrict__ PSM,
                                               const float* __restrict__ cn,
                                               float* __restrict__ outC) {
    int k = blockIdx.x, tid = threadIdx.x;
    __shared__ float red[4];

    float msum = 0.f;
    for (int p = tid; p < SINK_BLOCKS; p += 256) msum += PSM[(size_t)p * KC + k];
    for (int o = 32; o; o >>= 1) msum += __shfl_xor(msum, o);
    if ((tid & 63) == 0) red[tid >> 6] = msum;
    __syncthreads();
    float mk = fmaxf(red[0] + red[1] + red[2] + red[3], 1e-6f);
    __syncthreads();

    float w[3];
#pragma unroll
    for (int g = 0; g < 3; ++g) w[g] = W[k * DIM + tid + g * 256] / mk;

    float ss = w[0] * w[0] + w[1] * w[1] + w[2] * w[2];
    for (int o = 32; o; o >>= 1) ss += __shfl_xor(ss, o);
    if ((tid & 63) == 0) red[tid >> 6] = ss;
    __syncthreads();
    ss = red[0] + red[1] + red[2] + red[3];
    float n1 = fmaxf(sqrtf(ss), 1e-12f);
    __syncthreads();

    float u0 = 0.99f * cn[k * DIM + tid]       + 0.01f * (w[0] / n1);
    float u1 = 0.99f * cn[k * DIM + tid + 256] + 0.01f * (w[1] / n1);
    float u2 = 0.99f * cn[k * DIM + tid + 512] + 0.01f * (w[2] / n1);
    float ss2 = u0 * u0 + u1 * u1 + u2 * u2;
    for (int o = 32; o; o >>= 1) ss2 += __shfl_xor(ss2, o);
    if ((tid & 63) == 0) red[tid >> 6] = ss2;
    __syncthreads();
    ss2 = red[0] + red[1] + red[2] + red[3];
    float n2 = fmaxf(sqrtf(ss2), 1e-12f);

    outC[k * DIM + tid]       = u0 / n2;
    outC[k * DIM + tid + 256] = u1 / n2;
    outC[k * DIM + tid + 512] = u2 / n2;
}

extern "C" void kernel_launch(void* const* d_in, const int* in_sizes, int n_in,
                              void* d_out, int out_size, void* d_ws, size_t ws_size,
                              hipStream_t stream) {
    const float* F = (const float*)d_in[0];        // [65536][768]
    const float* centers = (const float*)d_in[1];  // [64][768]
    float* out = (float*)d_out;
    float* A = out;                                 // assignments [65536][64]
    float* outC = out + (size_t)M_TOTAL * KC;       // updated centers [64][768]

    float* w = (float*)d_ws;                        // ws = 768 MiB
    float* cn   = w;                                // 49152
    short* cnbf = (short*)(w + 49152);              // 24576 float slots
    float* R0   = w + 73728;                        // 64
    float* R1   = w + 73792;                        // 64
    float* R2   = w + 73856;                        // 64
    float* invn = w + 74048;                        // 65536
    float* cbuf = w + 139584;                       // 65536
    float* E    = w + 205120;                       // 4194304 (pre-swizzled layout)
    short* Qbf  = (short*)(w + 4399424);            // 2097152 float slots (8 MiB)
    float* PS0  = w + 6496576;                      // 1024*64
    float* PS1  = w + 6562112;                      // 512*64
    float* PS2  = w + 6594880;                      // 512*64
    float* PSM  = w + 6627648;                      // 512*64
    float* partial = w + 6660416;                   // MSEG*64*768 = 6291456 (24 MiB)
    float* weighted = w + 12951872;                 // 49152

    k_centers<<<KC, 256, 0, stream>>>(centers, cn, cnbf);
    k_logits<<<LOGITS_BLOCKS, 256, 0, stream>>>(F, cnbf, E, invn, PS0);
    k_redR<0><<<1, 1024, 0, stream>>>(PS0, LOGITS_BLOCKS, nullptr, R0);
    k_sink<0><<<SINK_BLOCKS, 256, 0, stream>>>(E, R0, invn, cbuf, PS1, A, Qbf);
    k_redR<1><<<1, 1024, 0, stream>>>(PS1, SINK_BLOCKS, R0, R1);
    k_sink<1><<<SINK_BLOCKS, 256, 0, stream>>>(E, R1, invn, cbuf, PS2, A, Qbf);
    k_redR<1><<<1, 1024, 0, stream>>>(PS2, SINK_BLOCKS, R1, R2);
    k_sink<2><<<SINK_BLOCKS, 256, 0, stream>>>(E, R2, invn, cbuf, PSM, A, Qbf);

    dim3 wgrid(DIM / DT, MSEG);
    k_weighted<<<wgrid, 256, 0, stream>>>(F, Qbf, partial);
    k_reducep<<<(KC * DIM) / 128, 128, 0, stream>>>(partial, weighted);
    k_final<<<KC, 256, 0, stream>>>(weighted, PSM, cn, outC);
}